// Round 1
// baseline (210.530 us; speedup 1.0000x reference)
//
#include <hip/hip_runtime.h>

// CubePadding: x [B,6,C,H,W] fp32 -> out [B,6,C,H+2P,W+2P] fp32. Pure gather/copy.
// R2: homogeneous block ranges.
//   Range A (interior): 1 lane per INPUT-aligned float4 (32 lanes/row, pow2 math).
//     aligned dwordx4 load -> __shfl_up lane-shift by 2 floats -> aligned dwordx4 store.
//     Zero branches, no gather path in these waves.
//   Range B (edges ~6%): whole blocks for v=0 / v=32 mixed groups + 4 halo rows,
//     per-element gen_map gather (verified in R0). Sub-ranges block-aligned.
// Face order: 0=back(fb) 1=down(fd) 2=front(ff) 3=left(fl) 4=right(fr) 5=top(ft)

constexpr int P = 2, B = 4, C = 64, H = 128, W = 128;
constexpr int Ho = H + 2 * P, Wo = W + 2 * P;   // 132, 132
constexpr int NV = Wo / 4;                      // 33 float4 groups per output row
constexpr int PLANES = B * 6 * C;               // 1536
constexpr int ROWS   = PLANES * H;              // 196608 input rows

// Range A: interior aligned copy, 32 lanes per input row
constexpr int NA   = ROWS * 32;                 // 6,291,456 lanes
constexpr int BLKA = NA / 256;                  // 24,576 blocks (exact)

// Range B: mixed edge groups (v=0, v=32) on interior rows + full halo rows
constexpr int NMIX  = ROWS * 2;                 // 393,216 (= 1536 blocks exact)
constexpr int NHALO = PLANES * 4 * NV;          // 202,752 (= 792 blocks exact)
constexpr int NB    = NMIX + NHALO;             // 595,968
constexpr int BLKB  = (NB + 255) / 256;         // 2328 blocks (exact)

// ---- halo source maps (verified in R0) ----
__device__ __forceinline__ void top_map(int f, int t, int w, int& sf, int& r, int& col) {
    switch (f) {
        case 0:  sf = 5; r = P - 1 - t; col = w;         break;
        case 1:  sf = 2; r = H - P + t; col = w;         break;
        case 2:  sf = 5; r = H - P + t; col = w;         break;
        case 3:  sf = 5; r = w;         col = t;         break;
        case 4:  sf = 5; r = w;         col = W - 1 - t; break;
        default: sf = 0; r = P - 1 - t; col = w;         break;
    }
}
__device__ __forceinline__ void bot_map(int f, int t, int w, int& sf, int& r, int& col) {
    switch (f) {
        case 0:  sf = 1; r = H - 1 - t; col = w;         break;
        case 1:  sf = 0; r = H - 1 - t; col = w;         break;
        case 2:  sf = 1; r = t;         col = w;         break;
        case 3:  sf = 1; r = w;         col = P - 1 - t; break;
        case 4:  sf = 1; r = w;         col = W - P + t; break;
        default: sf = 2; r = t;         col = w;         break;
    }
}
__device__ __forceinline__ void lft_map(int f, int h, int l, int& sf, int& r, int& col) {
    switch (f) {
        case 0:  sf = 4; r = h;         col = W - P + l; break;
        case 1:  sf = 3; r = H - 1 - l; col = h;         break;
        case 2:  sf = 3; r = h;         col = W - P + l; break;
        case 3:  sf = 0; r = h;         col = W - P + l; break;
        case 4:  sf = 2; r = h;         col = W - P + l; break;
        default: sf = 3; r = l;         col = h;         break;
    }
}
__device__ __forceinline__ void rgt_map(int f, int h, int rr, int& sf, int& r, int& col) {
    switch (f) {
        case 0:  sf = 3; r = h;          col = rr;        break;
        case 1:  sf = 4; r = H - P + rr; col = h;         break;
        case 2:  sf = 4; r = h;          col = rr;        break;
        case 3:  sf = 2; r = h;          col = rr;        break;
        case 4:  sf = 0; r = h;          col = rr;        break;
        default: sf = 4; r = P - 1 - rr; col = h;         break;
    }
}

// general per-element map: output (f,i,j) -> source (sf,r,col) within the same batch
__device__ __forceinline__ void gen_map(int f, int i, int j, int& sf, int& r, int& col) {
    bool in_h = (i >= P) && (i < H + P);
    bool in_w = (j >= P) && (j < W + P);
    if (in_h && in_w) {
        sf = f; r = i - P; col = j - P;
    } else if (!in_h) {
        int w = in_w ? (j - P) : (j < P ? 0 : W - 1);   // corners replicate strip edge
        if (i < P) top_map(f, i, w, sf, r, col);
        else       bot_map(f, i - H - P, w, sf, r, col);
    } else {
        if (j < P) lft_map(f, i - P, j,         sf, r, col);
        else       rgt_map(f, i - P, j - W - P, sf, r, col);
    }
}

__global__ __launch_bounds__(256) void cubepad_v5_kernel(const float* __restrict__ x,
                                                         float* __restrict__ out) {
    const int bid = blockIdx.x;
    const int tid = threadIdx.x;

    if (bid < BLKA) {
        // ---------------- Range A: branch-free interior copy ----------------
        const int idx = bid * 256 + tid;
        const int g   = tid & 31;           // input float4 group within row (0..31)
        const int row = idx >> 5;           // global input row, [0, ROWS)
        const int i   = row & (H - 1);
        const int p   = row >> 7;           // plane index (b*6+f)*C + c

        // aligned 16B load: in cols 4g .. 4g+3 of row
        const float4 v = *(const float4*)(x + ((size_t)row << 7) + (g << 2));

        // out group g (cols 4g..4g+3) = in cols 4g-2..4g+1 = in[g-1].zw ++ in[g].xy
        const float pz = __shfl_up(v.z, 1);
        const float pw = __shfl_up(v.w, 1);

        if (g != 0) {   // out groups 1..31 (cols 4..127); cols 0..3 / 128..131 in Range B
            const size_t o = (size_t)p * (Ho * Wo) + (size_t)(i + P) * Wo + (g << 2);
            *(float4*)(out + o) = make_float4(pz, pw, v.x, v.y);
        }
        return;
    }

    // ---------------- Range B: edge groups + halo rows (gather path) ----------------
    const int m = (bid - BLKA) * 256 + tid;
    if (m >= NB) return;

    int p, i_out, v;
    if (m < NMIX) {
        // mixed groups v=0 (out cols 0..3) and v=32 (out cols 128..131), interior rows
        const int row = m >> 1;
        v     = (m & 1) ? (NV - 1) : 0;
        i_out = (row & (H - 1)) + P;
        p     = row >> 7;
    } else {
        // full halo rows i_out in {0,1,130,131}, all 33 groups
        const int h = m - NMIX;
        const int g = h % NV;
        const int t = (h / NV) & 3;
        p     = h / (NV * 4);
        v     = g;
        i_out = (t < 2) ? t : (H + P + t - 2);
    }

    const int f  = (p / C) % 6;
    const int b  = p / (6 * C);
    const int bC = b * 6 * C + (p & (C - 1));   // b*6*C + c (src plane base helper)

    float4 val;
    float* vp = (float*)&val;
    #pragma unroll
    for (int e = 0; e < 4; ++e) {
        int sf, r, col;
        gen_map(f, i_out, 4 * v + e, sf, r, col);
        vp[e] = x[((size_t)(bC + sf * C)) * (H * W) + ((size_t)r << 7) + col];
    }
    const size_t o = (size_t)p * (Ho * Wo) + (size_t)i_out * Wo + ((size_t)v << 2);
    *(float4*)(out + o) = val;
}

extern "C" void kernel_launch(void* const* d_in, const int* in_sizes, int n_in,
                              void* d_out, int out_size, void* d_ws, size_t ws_size,
                              hipStream_t stream) {
    const float* x = (const float*)d_in[0];
    float* out = (float*)d_out;
    const int blocks = BLKA + BLKB;   // 26,904
    cubepad_v5_kernel<<<blocks, 256, 0, stream>>>(x, out);
}

// Round 3
// 191.374 us; speedup vs baseline: 1.1001x; 1.1001x over previous
//
#include <hip/hip_runtime.h>

// CubePadding: x [B,6,C,H,W] fp32 -> out [B,6,C,H+2P,W+2P] fp32. Pure gather/copy.
// R4 (v6b): v6 with the nontemporal-store type fixed (clang builtin requires a
//           native vector type, not HIP's float4 class -> use ext_vector_type(4)).
//   * flat output enumeration (dense hole-free store stream, like fillBuffer)
//   * NPT=4 independent output float4 groups per thread (grid-stride TOTAL/4,
//     exact division -> no bounds checks). All 4 loads issued before any store:
//     4x memory-level parallelism per wave vs v5's latency-bound 2.7 TB/s.
//   * nontemporal stores (output is write-once; keep L2 for input).
//   * interior fast path: 2x aligned float2 loads (8B-aligned).
// Face order: 0=back(fb) 1=down(fd) 2=front(ff) 3=left(fl) 4=right(fr) 5=top(ft)

typedef float f32x4 __attribute__((ext_vector_type(4)));

constexpr int P = 2, B = 4, C = 64, H = 128, W = 128;
constexpr int Ho = H + 2 * P, Wo = W + 2 * P;   // 132, 132
constexpr int NV = Wo / 4;                      // 33 float4 groups per output row
constexpr int TOTAL_V = B * 6 * C * Ho * NV;    // 6,690,816 output float4 groups
constexpr int NPT = 4;                          // groups per thread
constexpr int GSTRIDE = TOTAL_V / NPT;          // 1,672,704 (exact)
constexpr int BLOCKS = GSTRIDE / 256;           // 6,534 blocks (exact)

// ---- halo source maps (verified in R0) ----
__device__ __forceinline__ void top_map(int f, int t, int w, int& sf, int& r, int& col) {
    switch (f) {
        case 0:  sf = 5; r = P - 1 - t; col = w;         break;
        case 1:  sf = 2; r = H - P + t; col = w;         break;
        case 2:  sf = 5; r = H - P + t; col = w;         break;
        case 3:  sf = 5; r = w;         col = t;         break;
        case 4:  sf = 5; r = w;         col = W - 1 - t; break;
        default: sf = 0; r = P - 1 - t; col = w;         break;
    }
}
__device__ __forceinline__ void bot_map(int f, int t, int w, int& sf, int& r, int& col) {
    switch (f) {
        case 0:  sf = 1; r = H - 1 - t; col = w;         break;
        case 1:  sf = 0; r = H - 1 - t; col = w;         break;
        case 2:  sf = 1; r = t;         col = w;         break;
        case 3:  sf = 1; r = w;         col = P - 1 - t; break;
        case 4:  sf = 1; r = w;         col = W - P + t; break;
        default: sf = 2; r = t;         col = w;         break;
    }
}
__device__ __forceinline__ void lft_map(int f, int h, int l, int& sf, int& r, int& col) {
    switch (f) {
        case 0:  sf = 4; r = h;         col = W - P + l; break;
        case 1:  sf = 3; r = H - 1 - l; col = h;         break;
        case 2:  sf = 3; r = h;         col = W - P + l; break;
        case 3:  sf = 0; r = h;         col = W - P + l; break;
        case 4:  sf = 2; r = h;         col = W - P + l; break;
        default: sf = 3; r = l;         col = h;         break;
    }
}
__device__ __forceinline__ void rgt_map(int f, int h, int rr, int& sf, int& r, int& col) {
    switch (f) {
        case 0:  sf = 3; r = h;          col = rr;        break;
        case 1:  sf = 4; r = H - P + rr; col = h;         break;
        case 2:  sf = 4; r = h;          col = rr;        break;
        case 3:  sf = 2; r = h;          col = rr;        break;
        case 4:  sf = 0; r = h;          col = rr;        break;
        default: sf = 4; r = P - 1 - rr; col = h;         break;
    }
}

// general per-element map: output (f,i,j) -> source (sf,r,col) within the same batch
__device__ __forceinline__ void gen_map(int f, int i, int j, int& sf, int& r, int& col) {
    bool in_h = (i >= P) && (i < H + P);
    bool in_w = (j >= P) && (j < W + P);
    if (in_h && in_w) {
        sf = f; r = i - P; col = j - P;
    } else if (!in_h) {
        int w = in_w ? (j - P) : (j < P ? 0 : W - 1);   // corners replicate strip edge
        if (i < P) top_map(f, i, w, sf, r, col);
        else       bot_map(f, i - H - P, w, sf, r, col);
    } else {
        if (j < P) lft_map(f, i - P, j,         sf, r, col);
        else       rgt_map(f, i - P, j - W - P, sf, r, col);
    }
}

__global__ __launch_bounds__(256) void cubepad_v6_kernel(const float* __restrict__ x,
                                                         float* __restrict__ out) {
    const unsigned base = blockIdx.x * 256u + threadIdx.x;

    f32x4 vals[NPT];
    size_t offs[NPT];

    #pragma unroll
    for (int k = 0; k < NPT; ++k) {
        const unsigned idx  = base + (unsigned)(k * GSTRIDE);
        const unsigned v    = idx % NV;           // float4 group within output row
        const unsigned t1   = idx / NV;           // global output row
        const unsigned i    = t1 % Ho;            // output row within plane
        const unsigned rest = t1 / Ho;            // (b*6 + f)*C + c
        const int f  = (int)((rest >> 6) % 6u);                       // rest/C % 6
        const int bC = (int)(((rest >> 6) / 6u) * (6u * C) + (rest & 63u));  // b*6*C + c

        offs[k] = (size_t)t1 * Wo + 4u * v;

        const bool fast = (i >= P) & (i < H + P) & (v >= 1) & (v < NV - 1);
        if (fast) {
            // src: face f, row i-P, cols 4v-2 .. 4v+1 (8B-aligned start)
            const float* src = x + ((size_t)(bC + f * C)) * (H * W)
                                 + (size_t)(i - P) * W + (4u * v - P);
            const float2 lo = *(const float2*)(src);
            const float2 hi = *(const float2*)(src + 2);
            vals[k] = (f32x4){lo.x, lo.y, hi.x, hi.y};
        } else {
            #pragma unroll
            for (int e = 0; e < 4; ++e) {
                int sf, r, col;
                gen_map(f, (int)i, (int)(4u * v) + e, sf, r, col);
                vals[k][e] = x[((size_t)(bC + sf * C)) * (H * W) + (size_t)r * W + col];
            }
        }
    }

    #pragma unroll
    for (int k = 0; k < NPT; ++k) {
        __builtin_nontemporal_store(vals[k], (f32x4*)(out + offs[k]));
    }
}

extern "C" void kernel_launch(void* const* d_in, const int* in_sizes, int n_in,
                              void* d_out, int out_size, void* d_ws, size_t ws_size,
                              hipStream_t stream) {
    const float* x = (const float*)d_in[0];
    float* out = (float*)d_out;
    cubepad_v6_kernel<<<BLOCKS, 256, 0, stream>>>(x, out);
}

// Round 4
// 179.898 us; speedup vs baseline: 1.1703x; 1.0638x over previous
//
#include <hip/hip_runtime.h>

// CubePadding: x [B,6,C,H,W] fp32 -> out [B,6,C,H+2P,W+2P] fp32. Pure gather/copy.
// R5 (v7): v4's mapping (1 thread per output float4 group = max TLP, dense store
//          stream) with the vmem-issue-rate fix:
//   * fast path: ONE misaligned-by-8B float4 load (aligned(4) vec type; gfx9+
//     supports dword-aligned dwordx4) instead of 2x float2 -> 2 vmem instrs per
//     32B moved (v4: 3). We measured ~0.56 vmem/cyc/CU at 3.7 TB/s => issue-bound.
//   * interior-row edge lanes (v=0 / v=32) take a direct lft/rgt map path
//     (1 float2 + 2 scalars), NOT the full gen_map branch tree -- v4 serialized
//     that tree onto every wave. Only halo-row waves (3%) run gen_map.
//   * nontemporal stores (v6: WRITE_SIZE == exact output bytes).
// Face order: 0=back(fb) 1=down(fd) 2=front(ff) 3=left(fl) 4=right(fr) 5=top(ft)

typedef float f32x4 __attribute__((ext_vector_type(4)));
typedef f32x4 f32x4_u __attribute__((aligned(4)));   // permits 4B-aligned 16B loads

constexpr int P = 2, B = 4, C = 64, H = 128, W = 128;
constexpr int Ho = H + 2 * P, Wo = W + 2 * P;   // 132, 132
constexpr int NV = Wo / 4;                      // 33 float4 groups per output row
constexpr int TOTAL_V = B * 6 * C * Ho * NV;    // 6,690,816 = 26,136 * 256 exact
constexpr int BLOCKS = TOTAL_V / 256;           // 26,136

// ---- halo source maps (verified in R0) ----
__device__ __forceinline__ void top_map(int f, int t, int w, int& sf, int& r, int& col) {
    switch (f) {
        case 0:  sf = 5; r = P - 1 - t; col = w;         break;
        case 1:  sf = 2; r = H - P + t; col = w;         break;
        case 2:  sf = 5; r = H - P + t; col = w;         break;
        case 3:  sf = 5; r = w;         col = t;         break;
        case 4:  sf = 5; r = w;         col = W - 1 - t; break;
        default: sf = 0; r = P - 1 - t; col = w;         break;
    }
}
__device__ __forceinline__ void bot_map(int f, int t, int w, int& sf, int& r, int& col) {
    switch (f) {
        case 0:  sf = 1; r = H - 1 - t; col = w;         break;
        case 1:  sf = 0; r = H - 1 - t; col = w;         break;
        case 2:  sf = 1; r = t;         col = w;         break;
        case 3:  sf = 1; r = w;         col = P - 1 - t; break;
        case 4:  sf = 1; r = w;         col = W - P + t; break;
        default: sf = 2; r = t;         col = w;         break;
    }
}
__device__ __forceinline__ void lft_map(int f, int h, int l, int& sf, int& r, int& col) {
    switch (f) {
        case 0:  sf = 4; r = h;         col = W - P + l; break;
        case 1:  sf = 3; r = H - 1 - l; col = h;         break;
        case 2:  sf = 3; r = h;         col = W - P + l; break;
        case 3:  sf = 0; r = h;         col = W - P + l; break;
        case 4:  sf = 2; r = h;         col = W - P + l; break;
        default: sf = 3; r = l;         col = h;         break;
    }
}
__device__ __forceinline__ void rgt_map(int f, int h, int rr, int& sf, int& r, int& col) {
    switch (f) {
        case 0:  sf = 3; r = h;          col = rr;        break;
        case 1:  sf = 4; r = H - P + rr; col = h;         break;
        case 2:  sf = 4; r = h;          col = rr;        break;
        case 3:  sf = 2; r = h;          col = rr;        break;
        case 4:  sf = 0; r = h;          col = rr;        break;
        default: sf = 4; r = P - 1 - rr; col = h;         break;
    }
}

// general per-element map: output (f,i,j) -> source (sf,r,col) within the same batch
__device__ __forceinline__ void gen_map(int f, int i, int j, int& sf, int& r, int& col) {
    bool in_h = (i >= P) && (i < H + P);
    bool in_w = (j >= P) && (j < W + P);
    if (in_h && in_w) {
        sf = f; r = i - P; col = j - P;
    } else if (!in_h) {
        int w = in_w ? (j - P) : (j < P ? 0 : W - 1);   // corners replicate strip edge
        if (i < P) top_map(f, i, w, sf, r, col);
        else       bot_map(f, i - H - P, w, sf, r, col);
    } else {
        if (j < P) lft_map(f, i - P, j,         sf, r, col);
        else       rgt_map(f, i - P, j - W - P, sf, r, col);
    }
}

__global__ __launch_bounds__(256) void cubepad_v7_kernel(const float* __restrict__ x,
                                                         float* __restrict__ out) {
    const unsigned idx = blockIdx.x * 256u + threadIdx.x;   // grid is exact, no tail

    const unsigned v    = idx % (unsigned)NV;   // float4 group within output row
    const unsigned t1   = idx / (unsigned)NV;   // global output row
    const unsigned i    = t1 % (unsigned)Ho;    // output row within plane
    const unsigned rest = t1 / (unsigned)Ho;    // (b*6 + f)*C + c
    const int f  = (int)((rest >> 6) % 6u);
    const int bC = (int)(((rest >> 6) / 6u) * (6u * C) + (rest & 63u));  // b*6*C + c

    const size_t out_off = (size_t)t1 * Wo + 4u * v;
    const float* plane = x + ((size_t)(bC + f * C)) * (H * W);

    f32x4 val;

    if (i >= P && i < H + P) {
        const float* rowp = plane + (size_t)(i - P) * W;
        if (v - 1u < (unsigned)(NV - 2)) {
            // interior: src cols 4v-2 .. 4v+1, one 16B load at 8B-aligned addr
            val = *(const f32x4_u*)(rowp + 4u * v - P);
        } else if (v == 0u) {
            const float2 t = *(const float2*)(rowp);        // in cols 0,1
            int sf, r, col;
            lft_map(f, (int)i - P, 0, sf, r, col);
            val[0] = x[((size_t)(bC + sf * C)) * (H * W) + (size_t)r * W + col];
            lft_map(f, (int)i - P, 1, sf, r, col);
            val[1] = x[((size_t)(bC + sf * C)) * (H * W) + (size_t)r * W + col];
            val[2] = t.x; val[3] = t.y;
        } else {
            const float2 t = *(const float2*)(rowp + (W - P));  // in cols 126,127
            val[0] = t.x; val[1] = t.y;
            int sf, r, col;
            rgt_map(f, (int)i - P, 0, sf, r, col);
            val[2] = x[((size_t)(bC + sf * C)) * (H * W) + (size_t)r * W + col];
            rgt_map(f, (int)i - P, 1, sf, r, col);
            val[3] = x[((size_t)(bC + sf * C)) * (H * W) + (size_t)r * W + col];
        }
    } else {
        // halo rows (i in {0,1,130,131}): full gather, 3% of waves
        #pragma unroll
        for (int e = 0; e < 4; ++e) {
            int sf, r, col;
            gen_map(f, (int)i, (int)(4u * v) + e, sf, r, col);
            val[e] = x[((size_t)(bC + sf * C)) * (H * W) + (size_t)r * W + col];
        }
    }

    __builtin_nontemporal_store(val, (f32x4*)(out + out_off));
}

extern "C" void kernel_launch(void* const* d_in, const int* in_sizes, int n_in,
                              void* d_out, int out_size, void* d_ws, size_t ws_size,
                              hipStream_t stream) {
    const float* x = (const float*)d_in[0];
    float* out = (float*)d_out;
    cubepad_v7_kernel<<<BLOCKS, 256, 0, stream>>>(x, out);
}